// Round 2
// baseline (27925.256 us; speedup 1.0000x reference)
//
#include <hip/hip_runtime.h>
#include <cstdint>
#include <cstddef>

// SokobanNCA v2: flipped GEMM (D=[c_out][pixel]), weights streamed through a
// 2-buffer VGPR pipeline issued one phase ahead, swizzled 256B-stride LDS,
// packed b64 activation stores, coalesced d_out writes. 8 barriers/step.

#define NSAMPLES 2048
#define PM    112
#define ZROW  112
#define HA_OFF 0
#define HB_OFF 28928            // 113*256
#define A1_OFF HB_OFF           // A1 aliases hB (disjoint lifetime)
#define XS_OFF 57600            // HB_OFF + 112*256
#define LDS_TOTAL 62976         // XS_OFF + 112*48

typedef __attribute__((ext_vector_type(8))) short bf16x8;
typedef __attribute__((ext_vector_type(4))) float f32x4;
typedef __attribute__((ext_vector_type(2))) unsigned int u32x2;
typedef __attribute__((ext_vector_type(4))) unsigned int u32x4;

#define MFMA16(A, B, C) __builtin_amdgcn_mfma_f32_16x16x32_bf16((A), (B), (C), 0, 0, 0)

__device__ __forceinline__ short f2bf(float f) {
  unsigned u = __float_as_uint(f);
  return (short)((u + 0x7FFFu + ((u >> 16) & 1u)) >> 16);  // RNE
}

// ---------------- weight pre-pack (unchanged from r1; same layout works as A-frags) ----
__global__ void prepack_kernel(const float* __restrict__ w, short* __restrict__ dst,
                               int mode, int ntc, int Kact, int Nact, int total) {
  int idx = blockIdx.x * 256 + threadIdx.x;
  if (idx >= total) return;
  int j = idx & 7, l = (idx >> 3) & 63, t = idx >> 9;
  int nt = t % ntc, kt = t / ntc;
  int kg = kt * 32 + (l >> 4) * 8 + j;
  int nn = nt * 16 + (l & 15);
  float v = 0.f;
  if (mode == 0) {
    if (kg < Kact && nn < Nact) v = w[nn * Kact + kg];
  } else if (mode == 1) {
    if (kg < 45) { int s = kg / 5, cin = kg - 5 * s; v = w[nn * 45 + cin * 9 + s]; }
  } else {
    int s = kt >> 2;
    int kk = (kt & 3) * 32 + (l >> 4) * 8 + j;
    v = w[nn * 1152 + kk * 9 + s];
  }
  dst[idx] = f2bf(v);
}

// ---------------- device helpers ----------------
__device__ __forceinline__ void chain_mfma(const bf16x8 (&Wb)[2][4], const f32x4 (&pb)[2],
                                           const char* src, int n, int g16, int swzc,
                                           f32x4 (&acc)[2][7]) {
#pragma unroll
  for (int mt = 0; mt < 2; ++mt)
#pragma unroll
    for (int qt = 0; qt < 7; ++qt) acc[mt][qt] = pb[mt];
#pragma unroll
  for (int kt = 0; kt < 4; ++kt) {
#pragma unroll
    for (int qt = 0; qt < 7; ++qt) {
      bf16x8 Bf = *(const bf16x8*)(src + (16 * qt + n) * 256 + (((kt * 64) | g16) ^ swzc));
      acc[0][qt] = MFMA16(Wb[0][kt], Bf, acc[0][qt]);
      acc[1][qt] = MFMA16(Wb[1][kt], Bf, acc[1][qt]);
    }
  }
}

__device__ __forceinline__ void store_h(const f32x4 (&acc)[2][7], char* dst,
                                        int n, int woff0, int woff1) {
#pragma unroll
  for (int mt = 0; mt < 2; ++mt) {
    int wo = mt ? woff1 : woff0;
#pragma unroll
    for (int qt = 0; qt < 7; ++qt) {
      f32x4 v = acc[mt][qt];
      unsigned lo = (unsigned)(unsigned short)f2bf(fmaxf(v.x, 0.f)) |
                    ((unsigned)(unsigned short)f2bf(fmaxf(v.y, 0.f)) << 16);
      unsigned hi = (unsigned)(unsigned short)f2bf(fmaxf(v.z, 0.f)) |
                    ((unsigned)(unsigned short)f2bf(fmaxf(v.w, 0.f)) << 16);
      u32x2 wv = {lo, hi};
      *(u32x2*)(dst + (16 * qt + n) * 256 + wo) = wv;
    }
  }
}

// ---------------- main kernel ----------------
__global__ __launch_bounds__(256, 2) void nca_kernel(
    const float* __restrict__ x_in,
    const float* __restrict__ b1p, const float* __restrict__ b2p,
    const float* __restrict__ b3p, const float* __restrict__ b4p,
    const float* __restrict__ b5p, const float* __restrict__ b6p,
    const float* __restrict__ b7p,
    const short* __restrict__ W1, const short* __restrict__ W2,
    const short* __restrict__ W3, const short* __restrict__ W4,
    const short* __restrict__ W5, const short* __restrict__ W6,
    const short* __restrict__ W7,
    const int* __restrict__ steps_ptr, float* __restrict__ d_out) {
  __shared__ __align__(16) char lds[LDS_TOTAL];
  char* hA = lds + HA_OFF;
  char* hB = lds + HB_OFF;
  char* A1 = lds + A1_OFF;
  float* xs = (float*)(lds + XS_OFF);  // [112][12] f32, rows 48 B

  const int tid = threadIdx.x;
  const int sample = blockIdx.x;
  const int w = tid >> 6;
  const int l = tid & 63;
  const int n = l & 15;
  const int g = l >> 4;
  const int g16 = g << 4;
  const int swzc = (n & 7) << 4;
  const int steps = *steps_ptr;
  const float steps_f = (float)steps;
  const f32x4 fz = {0.f, 0.f, 0.f, 0.f};

  // packed write offsets per owned M-tile (c_out tiles 2w, 2w+1)
  const int woff0 = ((32 * (2 * w)) | (8 * g)) ^ swzc;
  const int woff1 = ((32 * (2 * w + 1)) | (8 * g)) ^ swzc;

  // per-lane pixel geometry per q-tile: rc = rr*32+cc, invalid -> huge
  int rc[7];
#pragma unroll
  for (int qt = 0; qt < 7; ++qt) {
    int p = 16 * qt + n;
    if (p < 100) { int r = p / 10; rc[qt] = r * 32 + (p - 10 * r); }
    else rc[qt] = 0x4000;
  }

  // zero ZROW of hA
  if (tid < 64) *(unsigned*)(hA + ZROW * 256 + tid * 4) = 0;
  // load x state
  for (int i = tid; i < 500; i += 256) {
    int c = i / 100, px = i - 100 * c;
    xs[px * 12 + c] = x_in[(size_t)sample * 500 + i];
  }
  // resident c7 bias
  f32x4 b7v = fz;
  if (g == 0) b7v = *(const f32x4*)&b7p[0];
  else if (g == 1) b7v.x = b7p[4];

  // weight stream buffers
  bf16x8 P0w[2][4], P1w[2][4];
  f32x4 pb0[2], pb1[2];

#define ISSUE_W(BUF, WP, NKT) { _Pragma("unroll") \
  for (int mt_ = 0; mt_ < 2; ++mt_) { _Pragma("unroll") \
    for (int kt_ = 0; kt_ < (NKT); ++kt_) \
      BUF[mt_][kt_] = *(const bf16x8*)&WP[(((kt_) * 8 + 2 * w + mt_) * 64 + l) * 8]; } }
#define ISSUE_W2S(BUF, S) { _Pragma("unroll") \
  for (int mt_ = 0; mt_ < 2; ++mt_) { _Pragma("unroll") \
    for (int kt_ = 0; kt_ < 4; ++kt_) \
      BUF[mt_][kt_] = *(const bf16x8*)&W2[((((S) * 4 + kt_) * 8 + 2 * w + mt_) * 64 + l) * 8]; } }
#define ISSUE_B(PB, BP) { PB[0] = *(const f32x4*)&BP[16 * (2 * w) + 4 * g]; \
                          PB[1] = *(const f32x4*)&BP[16 * (2 * w + 1) + 4 * g]; }
#define C2S(S, CUR) { \
  constexpr int dr_ = (S) / 3 - 1, dc_ = (S) % 3 - 1, doff_ = dr_ * 10 + dc_; \
  _Pragma("unroll") for (int qt_ = 0; qt_ < 7; ++qt_) { \
    bool ok_ = ((unsigned)((rc[qt_] >> 5) + dr_) < 10u) && \
               ((unsigned)((rc[qt_] & 31) + dc_) < 10u); \
    int prow_ = ok_ ? (16 * qt_ + n + doff_) : ZROW; \
    const char* rb_ = hA + prow_ * 256; \
    int swz_ = (prow_ & 7) << 4; \
    _Pragma("unroll") for (int kt_ = 0; kt_ < 4; ++kt_) { \
      bf16x8 Bf_ = *(const bf16x8*)(rb_ + (((kt_ * 64) | g16) ^ swz_)); \
      acc[0][qt_] = MFMA16(CUR[0][kt_], Bf_, acc[0][qt_]); \
      acc[1][qt_] = MFMA16(CUR[1][kt_], Bf_, acc[1][qt_]); \
    } } }

  // prefetch step-0 c1/c2 weights
  ISSUE_W(P0w, W1, 2); ISSUE_B(pb0, b1p);
  ISSUE_W2S(P1w, 0);   ISSUE_B(pb1, b2p);
  __syncthreads();

  for (int step = 0; step < steps; ++step) {
    // ---- phase A: copy out states[step-1] (coalesced) + im2col build ----
    if (step > 0) {
      size_t sb = 1024000u + ((size_t)(step - 1) * NSAMPLES + sample) * 500u;
      for (int i = tid; i < 500; i += 256) {
        int c = i / 100, px = i - 100 * c;
        d_out[sb + i] = xs[px * 12 + c];
      }
    }
    if (tid < PM) {
      int p = tid;
      bool pv = p < 100;
      int pc = pv ? p : 99;
      int r = pc / 10, c0 = pc - 10 * r;
      unsigned short sh[48];
#pragma unroll
      for (int kk = 45; kk < 48; ++kk) sh[kk] = 0;
#pragma unroll
      for (int s = 0; s < 9; ++s) {
        int dr = s / 3 - 1, dc = s - 3 * (s / 3) - 1;
        f32x4 xv = fz; float x4v = 0.f;
        if (pv && (unsigned)(r + dr) < 10u && (unsigned)(c0 + dc) < 10u) {
          const float* xr = &xs[(p + dr * 10 + dc) * 12];
          xv = *(const f32x4*)xr; x4v = xr[4];
        }
        sh[5 * s + 0] = (unsigned short)f2bf(xv.x);
        sh[5 * s + 1] = (unsigned short)f2bf(xv.y);
        sh[5 * s + 2] = (unsigned short)f2bf(xv.z);
        sh[5 * s + 3] = (unsigned short)f2bf(xv.w);
        sh[5 * s + 4] = (unsigned short)f2bf(x4v);
      }
      int swzr = (p & 7) << 4;
      char* arow = A1 + p * 128;
#pragma unroll
      for (int j = 0; j < 6; ++j) {
        u32x4 wv = {(unsigned)sh[8 * j] | ((unsigned)sh[8 * j + 1] << 16),
                    (unsigned)sh[8 * j + 2] | ((unsigned)sh[8 * j + 3] << 16),
                    (unsigned)sh[8 * j + 4] | ((unsigned)sh[8 * j + 5] << 16),
                    (unsigned)sh[8 * j + 6] | ((unsigned)sh[8 * j + 7] << 16)};
        *(u32x4*)(arow + ((16 * j) ^ swzr)) = wv;
      }
      u32x4 z4 = {0, 0, 0, 0};
      *(u32x4*)(arow + (96 ^ swzr)) = z4;
      *(u32x4*)(arow + (112 ^ swzr)) = z4;
    }
    __syncthreads();

    // ---- c1: A1 @ W1 (K=64) -> hA ; issue W2 s1 -> P0 ----
    {
      f32x4 acc[2][7];
#pragma unroll
      for (int mt = 0; mt < 2; ++mt)
#pragma unroll
        for (int qt = 0; qt < 7; ++qt) acc[mt][qt] = pb0[mt];
#pragma unroll
      for (int kt = 0; kt < 2; ++kt) {
#pragma unroll
        for (int qt = 0; qt < 7; ++qt) {
          bf16x8 Bf = *(const bf16x8*)(A1 + (16 * qt + n) * 128 + (((kt * 64) | g16) ^ swzc));
          acc[0][qt] = MFMA16(P0w[0][kt], Bf, acc[0][qt]);
          acc[1][qt] = MFMA16(P0w[1][kt], Bf, acc[1][qt]);
        }
      }
      ISSUE_W2S(P0w, 1);
      store_h(acc, hA, n, woff0, woff1);
    }
    __syncthreads();

    // ---- c2: 3x3 shift-decomposed, barrier-free s-loop with 1-slice-ahead stream ----
    {
      f32x4 acc[2][7];
#pragma unroll
      for (int mt = 0; mt < 2; ++mt)
#pragma unroll
        for (int qt = 0; qt < 7; ++qt) acc[mt][qt] = pb1[mt];
      C2S(0, P1w) ISSUE_W2S(P1w, 2)
      C2S(1, P0w) ISSUE_W2S(P0w, 3)
      C2S(2, P1w) ISSUE_W2S(P1w, 4)
      C2S(3, P0w) ISSUE_W2S(P0w, 5)
      C2S(4, P1w) ISSUE_W2S(P1w, 6)
      C2S(5, P0w) ISSUE_W2S(P0w, 7)
      C2S(6, P1w) ISSUE_W2S(P1w, 8)
      C2S(7, P0w) { ISSUE_W(P0w, W3, 4); ISSUE_B(pb0, b3p); }
      C2S(8, P1w)
      store_h(acc, hB, n, woff0, woff1);
    }
    __syncthreads();

    // ---- c3: hB -> hA ; issue W4 -> P1 ----
    {
      f32x4 acc[2][7];
      chain_mfma(P0w, pb0, hB, n, g16, swzc, acc);
      ISSUE_W(P1w, W4, 4); ISSUE_B(pb1, b4p);
      store_h(acc, hA, n, woff0, woff1);
    }
    __syncthreads();
    // ---- c4: hA -> hB ; issue W5 -> P0 ----
    {
      f32x4 acc[2][7];
      chain_mfma(P1w, pb1, hA, n, g16, swzc, acc);
      ISSUE_W(P0w, W5, 4); ISSUE_B(pb0, b5p);
      store_h(acc, hB, n, woff0, woff1);
    }
    __syncthreads();
    // ---- c5: hB -> hA ; issue W6 -> P1 ----
    {
      f32x4 acc[2][7];
      chain_mfma(P0w, pb0, hB, n, g16, swzc, acc);
      ISSUE_W(P1w, W6, 4); ISSUE_B(pb1, b6p);
      store_h(acc, hA, n, woff0, woff1);
    }
    __syncthreads();
    // ---- c6: hA -> hB ; issue W7 -> P0 (mt0 slot only) ----
    {
      f32x4 acc[2][7];
      chain_mfma(P1w, pb1, hA, n, g16, swzc, acc);
#pragma unroll
      for (int kt_ = 0; kt_ < 4; ++kt_)
        P0w[0][kt_] = *(const bf16x8*)&W7[(kt_ * 64 + l) * 8];
      store_h(acc, hB, n, woff0, woff1);
    }
    __syncthreads();

    // ---- c7 (128->5) + residual + softmax, pixel-partitioned across waves ----
    {
      float invT = 1.f / fmaxf(1.f - (float)step / steps_f, 0.5f);
#pragma unroll
      for (int rep = 0; rep < 2; ++rep) {
        int qt = 2 * w + rep;
        if (qt < 7) {
          f32x4 a = b7v;
#pragma unroll
          for (int kt = 0; kt < 4; ++kt) {
            bf16x8 Bf = *(const bf16x8*)(hB + (16 * qt + n) * 256 + (((kt * 64) | g16) ^ swzc));
            a = MFMA16(P0w[0][kt], Bf, a);
          }
          float c4v = __shfl_xor(a.x, 16);
          int px = 16 * qt + n;
          if (g == 0 && px < 100) {
            float* xr = &xs[px * 12];
            f32x4 xo = *(f32x4*)xr; float x4 = xr[4];
            float v0 = (xo.x + a.x) * invT, v1 = (xo.y + a.y) * invT;
            float v2 = (xo.z + a.z) * invT, v3 = (xo.w + a.w) * invT;
            float v4 = (x4 + c4v) * invT;
            float m = fmaxf(fmaxf(fmaxf(v0, v1), fmaxf(v2, v3)), v4);
            float e0 = __expf(v0 - m), e1 = __expf(v1 - m), e2 = __expf(v2 - m);
            float e3 = __expf(v3 - m), e4 = __expf(v4 - m);
            float inv = 1.f / (e0 + e1 + e2 + e3 + e4);
            f32x4 pv = {e0 * inv, e1 * inv, e2 * inv, e3 * inv};
            *(f32x4*)xr = pv; xr[4] = e4 * inv;
          }
        }
      }
      // prefetch next step's c1/c2 weights (harmless on last step)
      ISSUE_W(P0w, W1, 2); ISSUE_B(pb0, b1p);
      ISSUE_W2S(P1w, 0);   ISSUE_B(pb1, b2p);
    }
    __syncthreads();
  }

  // ---- final outputs: x_final + states[steps-1] ----
  {
    size_t sb = 1024000u + ((size_t)(steps - 1) * NSAMPLES + sample) * 500u;
    size_t fb = (size_t)sample * 500u;
    for (int i = tid; i < 500; i += 256) {
      int c = i / 100, px = i - 100 * c;
      float v = xs[px * 12 + c];
      d_out[fb + i] = v;
      d_out[sb + i] = v;
    }
  }
#undef ISSUE_W
#undef ISSUE_W2S
#undef ISSUE_B
#undef C2S
}

// ---------------- launch ----------------
extern "C" void kernel_launch(void* const* d_in, const int* in_sizes, int n_in,
                              void* d_out, int out_size, void* d_ws, size_t ws_size,
                              hipStream_t stream) {
  const float* x   = (const float*)d_in[0];
  const float* wp1 = (const float*)d_in[1];
  const float* bp1 = (const float*)d_in[2];
  const float* wp2 = (const float*)d_in[3];
  const float* bp2 = (const float*)d_in[4];
  const float* wp3 = (const float*)d_in[5];
  const float* bp3 = (const float*)d_in[6];
  const float* wu1 = (const float*)d_in[7];
  const float* bu1 = (const float*)d_in[8];
  const float* wu2 = (const float*)d_in[9];
  const float* bu2 = (const float*)d_in[10];
  const float* wu3 = (const float*)d_in[11];
  const float* bu3 = (const float*)d_in[12];
  const float* wu4 = (const float*)d_in[13];
  const float* bu4 = (const float*)d_in[14];
  const int* steps = (const int*)d_in[15];

  short* W1 = (short*)d_ws;          // [2][8][512]
  short* W2 = W1 + 8192;             // [36][8][512]
  short* W3 = W2 + 147456;           // [4][8][512]
  short* W4 = W3 + 16384;
  short* W5 = W4 + 16384;
  short* W6 = W5 + 16384;
  short* W7 = W6 + 16384;            // [4][1][512]

  prepack_kernel<<<(8192   + 255) / 256, 256, 0, stream>>>(wp1, W1, 1, 8, 45,   128, 8192);
  prepack_kernel<<<(147456 + 255) / 256, 256, 0, stream>>>(wp2, W2, 2, 8, 1152, 128, 147456);
  prepack_kernel<<<(16384  + 255) / 256, 256, 0, stream>>>(wp3, W3, 0, 8, 128,  128, 16384);
  prepack_kernel<<<(16384  + 255) / 256, 256, 0, stream>>>(wu1, W4, 0, 8, 128,  128, 16384);
  prepack_kernel<<<(16384  + 255) / 256, 256, 0, stream>>>(wu2, W5, 0, 8, 128,  128, 16384);
  prepack_kernel<<<(16384  + 255) / 256, 256, 0, stream>>>(wu3, W6, 0, 8, 128,  128, 16384);
  prepack_kernel<<<(2048   + 255) / 256, 256, 0, stream>>>(wu4, W7, 0, 1, 128,  5,   2048);

  nca_kernel<<<NSAMPLES, 256, 0, stream>>>(
      x, bp1, bp2, bp3, bu1, bu2, bu3, bu4,
      W1, W2, W3, W4, W5, W6, W7, steps, (float*)d_out);
}

// Round 3
// 5239.748 us; speedup vs baseline: 5.3295x; 5.3295x over previous
//
#include <hip/hip_runtime.h>
#include <cstdint>
#include <cstddef>

// SokobanNCA v3: flipped GEMM (D=[c_out][pixel], packed b64 stores) with
// TRANSIENT per-phase weight loads (no persistent weight regs -> no spills),
// runtime-looped c2 shifts and c3-c6 layers (I$-compact step body),
// nontemporal d_out stores (keep weights L2-resident). 8 barriers/step.

#define NSAMPLES 2048
#define PM    112
#define ZROW  112
#define HA_OFF 0
#define HB_OFF 28928            // 113*256
#define A1_OFF HB_OFF           // A1 aliases hB (disjoint lifetime)
#define XS_OFF 57600            // HB_OFF + 112*256
#define LDS_TOTAL 62976         // XS_OFF + 112*48

typedef __attribute__((ext_vector_type(8))) short bf16x8;
typedef __attribute__((ext_vector_type(4))) float f32x4;
typedef __attribute__((ext_vector_type(2))) unsigned int u32x2;
typedef __attribute__((ext_vector_type(4))) unsigned int u32x4;

#define MFMA16(A, B, C) __builtin_amdgcn_mfma_f32_16x16x32_bf16((A), (B), (C), 0, 0, 0)

__device__ __forceinline__ short f2bf(float f) {
  unsigned u = __float_as_uint(f);
  return (short)((u + 0x7FFFu + ((u >> 16) & 1u)) >> 16);  // RNE
}

// ---------------- weight pre-pack (unchanged; validated r1/r2) ----------------
__global__ void prepack_kernel(const float* __restrict__ w, short* __restrict__ dst,
                               int mode, int ntc, int Kact, int Nact, int total) {
  int idx = blockIdx.x * 256 + threadIdx.x;
  if (idx >= total) return;
  int j = idx & 7, l = (idx >> 3) & 63, t = idx >> 9;
  int nt = t % ntc, kt = t / ntc;
  int kg = kt * 32 + (l >> 4) * 8 + j;
  int nn = nt * 16 + (l & 15);
  float v = 0.f;
  if (mode == 0) {
    if (kg < Kact && nn < Nact) v = w[nn * Kact + kg];
  } else if (mode == 1) {
    if (kg < 45) { int s = kg / 5, cin = kg - 5 * s; v = w[nn * 45 + cin * 9 + s]; }
  } else {
    int s = kt >> 2;
    int kk = (kt & 3) * 32 + (l >> 4) * 8 + j;
    v = w[nn * 1152 + kk * 9 + s];
  }
  dst[idx] = f2bf(v);
}

// ---------------- device helpers (validated in r2) ----------------
__device__ __forceinline__ void chain_mfma(const bf16x8 (&Wb)[2][4], const f32x4 (&pb)[2],
                                           const char* src, int n, int g16, int swzc,
                                           f32x4 (&acc)[2][7]) {
#pragma unroll
  for (int mt = 0; mt < 2; ++mt)
#pragma unroll
    for (int qt = 0; qt < 7; ++qt) acc[mt][qt] = pb[mt];
#pragma unroll
  for (int kt = 0; kt < 4; ++kt) {
#pragma unroll
    for (int qt = 0; qt < 7; ++qt) {
      bf16x8 Bf = *(const bf16x8*)(src + (16 * qt + n) * 256 + (((kt * 64) | g16) ^ swzc));
      acc[0][qt] = MFMA16(Wb[0][kt], Bf, acc[0][qt]);
      acc[1][qt] = MFMA16(Wb[1][kt], Bf, acc[1][qt]);
    }
  }
}

__device__ __forceinline__ void store_h(const f32x4 (&acc)[2][7], char* dst,
                                        int n, int woff0, int woff1) {
#pragma unroll
  for (int mt = 0; mt < 2; ++mt) {
    int wo = mt ? woff1 : woff0;
#pragma unroll
    for (int qt = 0; qt < 7; ++qt) {
      f32x4 v = acc[mt][qt];
      unsigned lo = (unsigned)(unsigned short)f2bf(fmaxf(v.x, 0.f)) |
                    ((unsigned)(unsigned short)f2bf(fmaxf(v.y, 0.f)) << 16);
      unsigned hi = (unsigned)(unsigned short)f2bf(fmaxf(v.z, 0.f)) |
                    ((unsigned)(unsigned short)f2bf(fmaxf(v.w, 0.f)) << 16);
      u32x2 wv = {lo, hi};
      *(u32x2*)(dst + (16 * qt + n) * 256 + wo) = wv;
    }
  }
}

// ---------------- main kernel ----------------
__global__ __launch_bounds__(256, 2) void nca_kernel(
    const float* __restrict__ x_in,
    const float* __restrict__ b1p, const float* __restrict__ b2p,
    const float* __restrict__ b3p, const float* __restrict__ b4p,
    const float* __restrict__ b5p, const float* __restrict__ b6p,
    const float* __restrict__ b7p,
    const short* __restrict__ W1, const short* __restrict__ W2,
    const short* __restrict__ W3,   // W3..W6 contiguous: W3 + li*16384
    const short* __restrict__ W7,
    const int* __restrict__ steps_ptr, float* __restrict__ d_out) {
  __shared__ __align__(16) char lds[LDS_TOTAL];
  char* hA = lds + HA_OFF;
  char* hB = lds + HB_OFF;
  char* A1 = lds + A1_OFF;
  float* xs = (float*)(lds + XS_OFF);  // [112][12] f32, rows 48 B

  const int tid = threadIdx.x;
  const int sample = blockIdx.x;
  const int w = tid >> 6;
  const int l = tid & 63;
  const int n = l & 15;
  const int g = l >> 4;
  const int g16 = g << 4;
  const int swzc = (n & 7) << 4;
  const int steps = *steps_ptr;
  const float steps_f = (float)steps;
  const f32x4 fz = {0.f, 0.f, 0.f, 0.f};

  // packed write offsets per owned M-tile (c_out tiles 2w, 2w+1)
  const int woff0 = ((32 * (2 * w)) | (8 * g)) ^ swzc;
  const int woff1 = ((32 * (2 * w + 1)) | (8 * g)) ^ swzc;

  // per-lane pixel geometry per q-tile: rc = rr*32+cc, invalid -> huge
  int rc[7];
#pragma unroll
  for (int qt = 0; qt < 7; ++qt) {
    int p = 16 * qt + n;
    if (p < 100) { int r = p / 10; rc[qt] = r * 32 + (p - 10 * r); }
    else rc[qt] = 0x4000;
  }

  // zero ZROW of hA
  if (tid < 64) *(unsigned*)(hA + ZROW * 256 + tid * 4) = 0;
  // load x state
  for (int i = tid; i < 500; i += 256) {
    int c = i / 100, px = i - 100 * c;
    xs[px * 12 + c] = x_in[(size_t)sample * 500 + i];
  }
  // resident c7 bias (tiny)
  f32x4 b7v = fz;
  if (g == 0) b7v = *(const f32x4*)&b7p[0];
  else if (g == 1) b7v.x = b7p[4];
  __syncthreads();

  for (int step = 0; step < steps; ++step) {
    // ---- phase A: copy out states[step-1] (coalesced, nontemporal) + im2col ----
    if (step > 0) {
      size_t sb = 1024000u + ((size_t)(step - 1) * NSAMPLES + sample) * 500u;
      for (int i = tid; i < 500; i += 256) {
        int c = i / 100, px = i - 100 * c;
        __builtin_nontemporal_store(xs[px * 12 + c], &d_out[sb + i]);
      }
    }
    if (tid < PM) {
      int p = tid;
      bool pv = p < 100;
      int pc = pv ? p : 99;
      int r = pc / 10, c0 = pc - 10 * r;
      unsigned short sh[48];
#pragma unroll
      for (int kk = 45; kk < 48; ++kk) sh[kk] = 0;
#pragma unroll
      for (int s = 0; s < 9; ++s) {
        int dr = s / 3 - 1, dc = s - 3 * (s / 3) - 1;
        f32x4 xv = fz; float x4v = 0.f;
        if (pv && (unsigned)(r + dr) < 10u && (unsigned)(c0 + dc) < 10u) {
          const float* xr = &xs[(p + dr * 10 + dc) * 12];
          xv = *(const f32x4*)xr; x4v = xr[4];
        }
        sh[5 * s + 0] = (unsigned short)f2bf(xv.x);
        sh[5 * s + 1] = (unsigned short)f2bf(xv.y);
        sh[5 * s + 2] = (unsigned short)f2bf(xv.z);
        sh[5 * s + 3] = (unsigned short)f2bf(xv.w);
        sh[5 * s + 4] = (unsigned short)f2bf(x4v);
      }
      int swzr = (p & 7) << 4;
      char* arow = A1 + p * 128;
#pragma unroll
      for (int j = 0; j < 6; ++j) {
        u32x4 wv = {(unsigned)sh[8 * j] | ((unsigned)sh[8 * j + 1] << 16),
                    (unsigned)sh[8 * j + 2] | ((unsigned)sh[8 * j + 3] << 16),
                    (unsigned)sh[8 * j + 4] | ((unsigned)sh[8 * j + 5] << 16),
                    (unsigned)sh[8 * j + 6] | ((unsigned)sh[8 * j + 7] << 16)};
        *(u32x4*)(arow + ((16 * j) ^ swzr)) = wv;
      }
      u32x4 z4 = {0, 0, 0, 0};
      *(u32x4*)(arow + (96 ^ swzr)) = z4;
      *(u32x4*)(arow + (112 ^ swzr)) = z4;
    }
    __syncthreads();

    // ---- c1: A1 @ W1 (K=64) -> hA, transient weights ----
    {
      bf16x8 Wf[2][2];
#pragma unroll
      for (int mt = 0; mt < 2; ++mt)
#pragma unroll
        for (int kt = 0; kt < 2; ++kt)
          Wf[mt][kt] = *(const bf16x8*)&W1[((kt * 8 + 2 * w + mt) * 64 + l) * 8];
      f32x4 pb0 = *(const f32x4*)&b1p[16 * (2 * w) + 4 * g];
      f32x4 pb1 = *(const f32x4*)&b1p[16 * (2 * w + 1) + 4 * g];
      f32x4 acc[2][7];
#pragma unroll
      for (int qt = 0; qt < 7; ++qt) { acc[0][qt] = pb0; acc[1][qt] = pb1; }
#pragma unroll
      for (int kt = 0; kt < 2; ++kt) {
#pragma unroll
        for (int qt = 0; qt < 7; ++qt) {
          bf16x8 Bf = *(const bf16x8*)(A1 + (16 * qt + n) * 128 + (((kt * 64) | g16) ^ swzc));
          acc[0][qt] = MFMA16(Wf[0][kt], Bf, acc[0][qt]);
          acc[1][qt] = MFMA16(Wf[1][kt], Bf, acc[1][qt]);
        }
      }
      store_h(acc, hA, n, woff0, woff1);
    }
    __syncthreads();

    // ---- c2: 3x3 shift-decomposed, RUNTIME s-loop, transient weights ----
    {
      f32x4 acc[2][7];
      {
        f32x4 pb0 = *(const f32x4*)&b2p[16 * (2 * w) + 4 * g];
        f32x4 pb1 = *(const f32x4*)&b2p[16 * (2 * w + 1) + 4 * g];
#pragma unroll
        for (int qt = 0; qt < 7; ++qt) { acc[0][qt] = pb0; acc[1][qt] = pb1; }
      }
#pragma unroll 1
      for (int s = 0; s < 9; ++s) {
        int s3 = s / 3;
        int dr = s3 - 1, dc = s - 3 * s3 - 1;
        int doff = dr * 10 + dc;
        const short* Wsl = W2 + s * 16384;
        bf16x8 Wf[2][4];
#pragma unroll
        for (int mt = 0; mt < 2; ++mt)
#pragma unroll
          for (int kt = 0; kt < 4; ++kt)
            Wf[mt][kt] = *(const bf16x8*)&Wsl[((kt * 8 + 2 * w + mt) * 64 + l) * 8];
#pragma unroll
        for (int qt = 0; qt < 7; ++qt) {
          bool ok = ((unsigned)((rc[qt] >> 5) + dr) < 10u) &&
                    ((unsigned)((rc[qt] & 31) + dc) < 10u);
          int prow = ok ? (16 * qt + n + doff) : ZROW;
          const char* rb = hA + prow * 256;
          int swz = (prow & 7) << 4;
#pragma unroll
          for (int kt = 0; kt < 4; ++kt) {
            bf16x8 Bf = *(const bf16x8*)(rb + (((kt * 64) | g16) ^ swz));
            acc[0][qt] = MFMA16(Wf[0][kt], Bf, acc[0][qt]);
            acc[1][qt] = MFMA16(Wf[1][kt], Bf, acc[1][qt]);
          }
        }
      }
      store_h(acc, hB, n, woff0, woff1);
    }
    __syncthreads();

    // ---- c3..c6: RUNTIME layer loop, ping-pong hB<->hA, transient weights ----
#pragma unroll 1
    for (int li = 0; li < 4; ++li) {
      const short* Wp = W3 + li * 16384;
      const float* bp = (li == 0) ? b3p : (li == 1) ? b4p : (li == 2) ? b5p : b6p;
      const char* src = (li & 1) ? hA : hB;
      char* dst = (li & 1) ? hB : hA;
      bf16x8 Wf[2][4];
#pragma unroll
      for (int mt = 0; mt < 2; ++mt)
#pragma unroll
        for (int kt = 0; kt < 4; ++kt)
          Wf[mt][kt] = *(const bf16x8*)&Wp[((kt * 8 + 2 * w + mt) * 64 + l) * 8];
      f32x4 pb[2];
      pb[0] = *(const f32x4*)&bp[16 * (2 * w) + 4 * g];
      pb[1] = *(const f32x4*)&bp[16 * (2 * w + 1) + 4 * g];
      f32x4 acc[2][7];
      chain_mfma(Wf, pb, src, n, g16, swzc, acc);
      store_h(acc, dst, n, woff0, woff1);
      __syncthreads();
    }

    // ---- c7 (128->5) + residual + softmax (validated r2 structure) ----
    {
      bf16x8 W7f[4];
#pragma unroll
      for (int kt = 0; kt < 4; ++kt)
        W7f[kt] = *(const bf16x8*)&W7[(kt * 64 + l) * 8];
      float invT = 1.f / fmaxf(1.f - (float)step / steps_f, 0.5f);
#pragma unroll
      for (int rep = 0; rep < 2; ++rep) {
        int qt = 2 * w + rep;
        if (qt < 7) {
          f32x4 a = b7v;
#pragma unroll
          for (int kt = 0; kt < 4; ++kt) {
            bf16x8 Bf = *(const bf16x8*)(hB + (16 * qt + n) * 256 + (((kt * 64) | g16) ^ swzc));
            a = MFMA16(W7f[kt], Bf, a);
          }
          float c4v = __shfl_xor(a.x, 16);
          int px = 16 * qt + n;
          if (g == 0 && px < 100) {
            float* xr = &xs[px * 12];
            f32x4 xo = *(f32x4*)xr; float x4 = xr[4];
            float v0 = (xo.x + a.x) * invT, v1 = (xo.y + a.y) * invT;
            float v2 = (xo.z + a.z) * invT, v3 = (xo.w + a.w) * invT;
            float v4 = (x4 + c4v) * invT;
            float m = fmaxf(fmaxf(fmaxf(v0, v1), fmaxf(v2, v3)), v4);
            float e0 = __expf(v0 - m), e1 = __expf(v1 - m), e2 = __expf(v2 - m);
            float e3 = __expf(v3 - m), e4 = __expf(v4 - m);
            float inv = 1.f / (e0 + e1 + e2 + e3 + e4);
            f32x4 pv = {e0 * inv, e1 * inv, e2 * inv, e3 * inv};
            *(f32x4*)xr = pv; xr[4] = e4 * inv;
          }
        }
      }
    }
    __syncthreads();
  }

  // ---- final outputs: x_final + states[steps-1] (nontemporal) ----
  {
    size_t sb = 1024000u + ((size_t)(steps - 1) * NSAMPLES + sample) * 500u;
    size_t fb = (size_t)sample * 500u;
    for (int i = tid; i < 500; i += 256) {
      int c = i / 100, px = i - 100 * c;
      float v = xs[px * 12 + c];
      __builtin_nontemporal_store(v, &d_out[fb + i]);
      __builtin_nontemporal_store(v, &d_out[sb + i]);
    }
  }
}

// ---------------- launch ----------------
extern "C" void kernel_launch(void* const* d_in, const int* in_sizes, int n_in,
                              void* d_out, int out_size, void* d_ws, size_t ws_size,
                              hipStream_t stream) {
  const float* x   = (const float*)d_in[0];
  const float* wp1 = (const float*)d_in[1];
  const float* bp1 = (const float*)d_in[2];
  const float* wp2 = (const float*)d_in[3];
  const float* bp2 = (const float*)d_in[4];
  const float* wp3 = (const float*)d_in[5];
  const float* bp3 = (const float*)d_in[6];
  const float* wu1 = (const float*)d_in[7];
  const float* bu1 = (const float*)d_in[8];
  const float* wu2 = (const float*)d_in[9];
  const float* bu2 = (const float*)d_in[10];
  const float* wu3 = (const float*)d_in[11];
  const float* bu3 = (const float*)d_in[12];
  const float* wu4 = (const float*)d_in[13];
  const float* bu4 = (const float*)d_in[14];
  const int* steps = (const int*)d_in[15];

  // packed bf16 weights in workspace (W3..W6 contiguous for runtime indexing)
  short* W1 = (short*)d_ws;          // [2][8][512]
  short* W2 = W1 + 8192;             // [36][8][512]
  short* W3 = W2 + 147456;           // 4 x [4][8][512] contiguous
  short* W4 = W3 + 16384;
  short* W5 = W4 + 16384;
  short* W6 = W5 + 16384;
  short* W7 = W6 + 16384;            // [4][1][512]

  prepack_kernel<<<(8192   + 255) / 256, 256, 0, stream>>>(wp1, W1, 1, 8, 45,   128, 8192);
  prepack_kernel<<<(147456 + 255) / 256, 256, 0, stream>>>(wp2, W2, 2, 8, 1152, 128, 147456);
  prepack_kernel<<<(16384  + 255) / 256, 256, 0, stream>>>(wp3, W3, 0, 8, 128,  128, 16384);
  prepack_kernel<<<(16384  + 255) / 256, 256, 0, stream>>>(wu1, W4, 0, 8, 128,  128, 16384);
  prepack_kernel<<<(16384  + 255) / 256, 256, 0, stream>>>(wu2, W5, 0, 8, 128,  128, 16384);
  prepack_kernel<<<(16384  + 255) / 256, 256, 0, stream>>>(wu3, W6, 0, 8, 128,  128, 16384);
  prepack_kernel<<<(2048   + 255) / 256, 256, 0, stream>>>(wu4, W7, 0, 1, 128,  5,   2048);

  nca_kernel<<<NSAMPLES, 256, 0, stream>>>(
      x, bp1, bp2, bp3, bu1, bu2, bu3, bu4,
      W1, W2, W3, W7, steps, (float*)d_out);
}